// Round 5
// baseline (259.328 us; speedup 1.0000x reference)
//
#include <hip/hip_runtime.h>

#define TILE 32
#define NCH 76

// Composed 5-tap weight tables (x64 scaling folded into eps constants).
// t_s: rows y0-2..y0+33, local col = gx - x0 + 4 (stride 44, float4-aligned staging)
// e_s: rows y0-1..y0+32, local col = gx - x0 + 4 (stride 41, odd: conflict-light)

__global__ __launch_bounds__(256, 8) void nms_loss_kernel(
    const float* __restrict__ tl, const float* __restrict__ pl,
    double* __restrict__ acc_d, float* __restrict__ acc_f,
    int H, int W)
{
    __shared__ __align__(16) float t_s[36][44];
    __shared__ float e_s[34][41];
    __shared__ float wsum[4];

    const int ch = blockIdx.z;
    const int y0 = blockIdx.y * TILE, x0 = blockIdx.x * TILE;
    const float* tc = tl + (size_t)ch * H * W;
    const float* pc = pl + (size_t)ch * H * W;
    const int tid = threadIdx.x;
    const bool bint = (y0 != 0) && (y0 != H - TILE) && (x0 != 0) && (x0 != W - TILE);

    if (bint) {
        // t: 36 rows x 11 float4 (global cols x0-4 .. x0+39, aligned)
        for (int i = tid; i < 36 * 11; i += 256) {
            int u = i / 11, c4 = (i - u * 11) * 4;
            *(float4*)&t_s[u][c4] = *(const float4*)(tc + (y0 + u - 2) * W + (x0 - 4 + c4));
        }
        // e: 34 rows x 10 float4 (global cols x0-4 .. x0+35)
        for (int i = tid; i < 34 * 10; i += 256) {
            int v = i / 10, c4 = (i - v * 10) * 4;
            float4 p4 = *(const float4*)(pc + (y0 + v - 1) * W + (x0 - 4 + c4));
            e_s[v][c4 + 0] = __expf(0.1f * p4.x);
            e_s[v][c4 + 1] = __expf(0.1f * p4.y);
            e_s[v][c4 + 2] = __expf(0.1f * p4.z);
            e_s[v][c4 + 3] = __expf(0.1f * p4.w);
        }
    } else {
        for (int i = tid; i < 36 * 44; i += 256) {
            int u = i / 44, w = i - u * 44;
            int gy = min(max(y0 + u - 2, 0), H - 1);
            int gx = min(max(x0 + w - 4, 0), W - 1);
            t_s[u][w] = tc[gy * W + gx];
        }
        for (int i = tid; i < 34 * 38; i += 256) {   // local cols 0..37 (need 3..36)
            int v = i / 38, w = i - v * 38;
            int gy = y0 + v - 1; gy = gy < 0 ? -gy : (gy >= H ? 2 * H - 2 - gy : gy);
            int gx = x0 + w - 4; gx = gx < 0 ? -gx : (gx >= W ? 2 * W - 2 - gx : gx);
            e_s[v][w] = __expf(0.1f * pc[gy * W + gx]);
        }
    }
    __syncthreads();

    const int r  = tid >> 3;           // output row 0..31
    const int cs = (tid & 7) << 2;     // output col base 0,4,..,28
    const int y  = y0 + r;

    // ---- vertical composed 5-tap weights ----
    float wss[5], wsd[5], wdd[5];
    if (y >= 2 && y <= H - 3) {
        wss[0]=1; wss[1]=4; wss[2]=6;  wss[3]=4;  wss[4]=1;
        wsd[0]=-1;wsd[1]=-2;wsd[2]=0;  wsd[3]=2;  wsd[4]=1;
        wdd[0]=1; wdd[1]=0; wdd[2]=-2; wdd[3]=0;  wdd[4]=1;
    } else if (y == 0) {
        wss[0]=0; wss[1]=0; wss[2]=10; wss[3]=5;  wss[4]=1;
        wsd[0]=0; wsd[1]=0; wsd[2]=-4; wsd[3]=3;  wsd[4]=1;
        wdd[0]=0; wdd[1]=0; wdd[2]=0;  wdd[3]=-1; wdd[4]=1;
    } else if (y == 1) {
        wss[0]=0; wss[1]=5; wss[2]=6;  wss[3]=4;  wss[4]=1;
        wsd[0]=0; wsd[1]=-3;wsd[2]=0;  wsd[3]=2;  wsd[4]=1;
        wdd[0]=0; wdd[1]=1; wdd[2]=-2; wdd[3]=0;  wdd[4]=1;
    } else if (y == H - 1) {
        wss[0]=1; wss[1]=5; wss[2]=10; wss[3]=0;  wss[4]=0;
        wsd[0]=-1;wsd[1]=-3;wsd[2]=4;  wsd[3]=0;  wsd[4]=0;
        wdd[0]=1; wdd[1]=-1;wdd[2]=0;  wdd[3]=0;  wdd[4]=0;
    } else { // y == H-2
        wss[0]=1; wss[1]=4; wss[2]=6;  wss[3]=5;  wss[4]=0;
        wsd[0]=-1;wsd[1]=-2;wsd[2]=0;  wsd[3]=3;  wsd[4]=0;
        wdd[0]=1; wdd[1]=0; wdd[2]=-2; wdd[3]=1;  wdd[4]=0;
    }

    // ---- vertical pass: 3 b128 reads/row, window = local cols cs+2 .. cs+9 ----
    float V1[8], V2[8], V3[8], mrow[4];
    #pragma unroll
    for (int jj = 0; jj < 8; ++jj) { V1[jj] = 0.f; V2[jj] = 0.f; V3[jj] = 0.f; }
    #pragma unroll
    for (int k = 0; k < 5; ++k) {
        float4 w0 = *(const float4*)&t_s[r + k][cs];
        float4 w1 = *(const float4*)&t_s[r + k][cs + 4];
        float4 w2 = *(const float4*)&t_s[r + k][cs + 8];
        float row[8] = {w0.z, w0.w, w1.x, w1.y, w1.z, w1.w, w2.x, w2.y};
        #pragma unroll
        for (int jj = 0; jj < 8; ++jj) {
            V1[jj] = fmaf(wss[k], row[jj], V1[jj]);
            V2[jj] = fmaf(wsd[k], row[jj], V2[jj]);
            V3[jj] = fmaf(wdd[k], row[jj], V3[jj]);
        }
        if (k == 2) { mrow[0] = row[2]; mrow[1] = row[3]; mrow[2] = row[4]; mrow[3] = row[5]; }
    }

    // ---- horizontal pass per pixel ----
    float xx4[4], xy4[4], yy4[4];
    #pragma unroll
    for (int j = 0; j < 4; ++j) {
        int x = x0 + cs + j;
        float xx, xy, yy;
        if (x >= 2 && x <= W - 3) {
            xx = (V1[j] + V1[j + 4]) - 2.f * V1[j + 2];
            xy = (V2[j + 4] - V2[j]) + 2.f * (V2[j + 3] - V2[j + 1]);
            yy = (V3[j] + V3[j + 4]) + 4.f * (V3[j + 1] + V3[j + 3]) + 6.f * V3[j + 2];
        } else {
            float hdd[5], hds[5], hss[5];
            if (x == 0) {
                hdd[0]=0; hdd[1]=0;  hdd[2]=0;  hdd[3]=-1; hdd[4]=1;
                hds[0]=0; hds[1]=0;  hds[2]=-2; hds[3]=1;  hds[4]=1;
                hss[0]=0; hss[1]=0;  hss[2]=10; hss[3]=5;  hss[4]=1;
            } else if (x == 1) {
                hdd[0]=0; hdd[1]=1;  hdd[2]=-2; hdd[3]=0;  hdd[4]=1;
                hds[0]=0; hds[1]=-3; hds[2]=0;  hds[3]=2;  hds[4]=1;
                hss[0]=0; hss[1]=5;  hss[2]=6;  hss[3]=4;  hss[4]=1;
            } else if (x == W - 1) {
                hdd[0]=1; hdd[1]=-1; hdd[2]=0;  hdd[3]=0;  hdd[4]=0;
                hds[0]=-1;hds[1]=-1; hds[2]=2;  hds[3]=0;  hds[4]=0;
                hss[0]=1; hss[1]=5;  hss[2]=10; hss[3]=0;  hss[4]=0;
            } else { // x == W-2
                hdd[0]=1; hdd[1]=0;  hdd[2]=-2; hdd[3]=1;  hdd[4]=0;
                hds[0]=-1;hds[1]=-2; hds[2]=0;  hds[3]=3;  hds[4]=0;
                hss[0]=1; hss[1]=4;  hss[2]=6;  hss[3]=5;  hss[4]=0;
            }
            xx = 0.f; xy = 0.f; yy = 0.f;
            #pragma unroll
            for (int m = 0; m < 5; ++m) {
                xx = fmaf(hdd[m], V1[j + m], xx);
                xy = fmaf(hds[m], V2[j + m], xy);
                yy = fmaf(hss[m], V3[j + m], yy);
            }
        }
        xx4[j] = xx; xy4[j] = xy; yy4[j] = yy;
    }

    // ---- tail: early unconditional e loads, branch-free select, log ----
    float partial = 0.f;
    const int er = r + 1;
    const float4 pv4 = *(const float4*)(pc + (size_t)y * W + x0 + cs);
    #pragma unroll
    for (int h = 0; h < 2; ++h) {
        const int b = cs + 3 + 2 * h;   // e cols b..b+3 cover this half's centers +-1
        float e0[4], e1[4], e2[4];
        #pragma unroll
        for (int q = 0; q < 4; ++q) {
            e0[q] = e_s[er - 1][b + q];
            e1[q] = e_s[er    ][b + q];
            e2[q] = e_s[er + 1][b + q];
        }
        #pragma unroll
        for (int jj = 0; jj < 2; ++jj) {
            const int j = 2 * h + jj;
            if (mrow[j] > 0.f) {
                float xx = xx4[j], xy = xy4[j], yy = yy4[j];   // 64x scaled
                float sa = 6.4e-6f - xy;                        // 64*(1e-7 - grad_xy)
                float s  = sa > 0.f ? 1.f : (sa < 0.f ? -1.f : 0.f);
                float q  = __fdividef(yy * s, xx + 6.4e-6f);
                float aq = fabsf(q);
                bool isH = aq < 0.41421356f;    // tan(22.5)
                bool isV = aq >= 2.41421356f;   // tan(67.5)
                const int qc = jj + 1;
                float E  = e1[qc];
                float dn = q > 0.f ? e2[qc - 1] : e2[qc + 1];
                float n1 = isH ? e1[qc + 1] : (isV ? e2[qc] : dn);
                float up = q > 0.f ? e0[qc + 1] : e0[qc - 1];
                float n2 = isH ? e1[qc - 1] : (isV ? e0[qc] : up);
                float f  = E + n1 + n2;
                float pv = (j == 0) ? pv4.x : (j == 1) ? pv4.y : (j == 2) ? pv4.z : pv4.w;
                float lr = 0.1f * pv - __logf(f + 1e-7f);
                partial += fminf(fmaxf(lr, -16.118095651f), 0.f);
            }
        }
    }

    // ---- block reduction ----
    for (int off = 32; off > 0; off >>= 1)
        partial += __shfl_down(partial, off, 64);
    if ((tid & 63) == 0) wsum[tid >> 6] = partial;
    __syncthreads();
    if (tid == 0) {
        float s = wsum[0] + wsum[1] + wsum[2] + wsum[3];
        if (acc_d) atomicAdd(&acc_d[ch], (double)s);
        else       atomicAdd(acc_f, s);
    }
}

__global__ void finalize_kernel(const double* acc_d, const float* acc_f,
                                float* out, int use_double, int nch, float inv_b)
{
    if (use_double) {
        double s = 0.0;
        for (int i = 0; i < nch; ++i) s += acc_d[i];
        out[0] = (float)(-s * (double)inv_b);
    } else {
        out[0] = -acc_f[0] * inv_b;
    }
}

extern "C" void kernel_launch(void* const* d_in, const int* in_sizes, int n_in,
                              void* d_out, int out_size, void* d_ws, size_t ws_size,
                              hipStream_t stream)
{
    const float* tl = (const float*)d_in[0];
    const float* pl = (const float*)d_in[1];
    float* out = (float*)d_out;

    const int H = 512, W = 512, B = 4;
    const int nch = NCH;

    double* acc_d = nullptr;
    float* acc_f = nullptr;
    int use_double = 0;
    if (ws_size >= nch * sizeof(double)) {
        acc_d = (double*)d_ws;
        use_double = 1;
        hipMemsetAsync(acc_d, 0, nch * sizeof(double), stream);
    } else {
        acc_f = out;
        hipMemsetAsync(out, 0, sizeof(float), stream);
    }

    dim3 grid(W / TILE, H / TILE, nch);
    nms_loss_kernel<<<grid, 256, 0, stream>>>(tl, pl, acc_d, acc_f, H, W);
    finalize_kernel<<<1, 1, 0, stream>>>(acc_d, acc_f ? acc_f : out, out,
                                         use_double, nch, 1.0f / (float)B);
}